// Round 5
// baseline (628.350 us; speedup 1.0000x reference)
//
#include <hip/hip_runtime.h>
#include <hip/hip_bf16.h>
#include <math.h>

typedef __hip_bfloat16 bf;

#define BB   16     // batch
#define CC   128    // channels
#define LL   4096   // H*W
#define DM   32     // d_model per chunk
#define DI   64     // d_inner
#define DSN  16     // d_state
#define GG   64     // 4 * BB sequences
#define NC   64     // scan chunks
#define CL   64     // LL / NC
#define TLV  61     // valid output columns per k1 tile (64 loaded, 3 head)
#define NT   68     // ceil(LL / TLV)
#define TL   64     // l-tile for k6

__device__ __forceinline__ float bf2f(bf x) { return __bfloat162float(x); }
__device__ __forceinline__ bf f2bf(float x) { return __float2bfloat16(x); }
__device__ __forceinline__ float blo(unsigned v) { return __uint_as_float(v << 16); }
__device__ __forceinline__ float bhi(unsigned v) { return __uint_as_float(v & 0xffff0000u); }
__device__ __forceinline__ float us2f(unsigned short v) { return __uint_as_float((unsigned)v << 16); }
__device__ __forceinline__ unsigned pack2(float a, float b) {
  bf ba = f2bf(a), bb = f2bf(b);
  unsigned short ua = *(unsigned short*)&ba, ub = *(unsigned short*)&bb;
  return (unsigned)ua | ((unsigned)ub << 16);
}

#if __has_builtin(__builtin_amdgcn_exp2f)
#define EXP2F(x) __builtin_amdgcn_exp2f(x)
#else
#define EXP2F(x) exp2f(x)
#endif

__device__ __forceinline__ float sigmoidf_(float x) { return 1.0f / (1.0f + __expf(-x)); }
__device__ __forceinline__ float softplusf_(float x) {
  return fmaxf(x, 0.0f) + log1pf(__expf(-fabsf(x)));
}
__device__ __forceinline__ void unpack8(uint4 v, float* o) {
  o[0] = blo(v.x); o[1] = bhi(v.x); o[2] = blo(v.y); o[3] = bhi(v.y);
  o[4] = blo(v.z); o[5] = bhi(v.z); o[6] = blo(v.w); o[7] = bhi(v.w);
}

// ---------------- K1: layernorm + in_proj(xi) + causal conv + silu -> u (bf16), xn (bf16) ----------------
// grid: BB * NT = 1088 blocks, 256 threads. Overlapping tiles: 64 columns loaded (l0-3 .. l0+60),
// 61 outputs. Phase A: thread=(g, col) computes xi[col][all 64 d] in registers (fully unrolled,
// no dynamic indexing -> no scratch), writes bf16 xi to LDS. Phase B: thread=(g, d) runs the conv.
__global__ __launch_bounds__(256) void k1_ln_conv(
    const float* __restrict__ input, const float* __restrict__ ln_g, const float* __restrict__ ln_b,
    const float* __restrict__ in_proj_w, const float* __restrict__ conv_w, const float* __restrict__ conv_b,
    bf* __restrict__ u_ws, bf* __restrict__ xn_ws) {
  __shared__ unsigned ldsbuf[8704];               // union: xnT fp32 [64][132] (33792B) / xiS bf16 [4][64][68] (34816B)
  __shared__ float mu_s[64], rs_s[64];
  float* xnT = (float*)ldsbuf;
  unsigned short* xiS = (unsigned short*)ldsbuf;
  int b = blockIdx.x / NT;
  int tile = blockIdx.x - b * NT;
  int l0 = tile * TLV;
  int tid = threadIdx.x;
  const float* inb = input + (size_t)b * CC * LL;
#pragma unroll
  for (int k = 0; k < 32; k++) {                  // fill 64 cols x 128 ch, coalesced over l
    int i = tid + k * 256;
    int j = i & 63, c = i >> 6;
    int l = l0 - 3 + j;
    xnT[j * 132 + c] = (l >= 0 && l < LL) ? inb[c * LL + l] : 0.0f;
  }
  __syncthreads();
  if (tid < 64) {
    float s = 0.f, s2 = 0.f;
    for (int c = 0; c < CC; c++) { float v = xnT[tid * 132 + c]; s += v; s2 = fmaf(v, v, s2); }
    float mu = s * (1.0f / CC);
    float var = s2 * (1.0f / CC) - mu * mu;
    mu_s[tid] = mu;
    rs_s[tid] = rsqrtf(var + 1e-5f);
  }
  __syncthreads();
#pragma unroll
  for (int k = 0; k < 32; k++) {                  // normalize; c wave-uniform -> scalar ln_g/ln_b
    int i = tid + k * 256;
    int j = i & 63, c = i >> 6;
    xnT[j * 132 + c] = (xnT[j * 132 + c] - mu_s[j]) * rs_s[j] * ln_g[c] + ln_b[c];
  }
  __syncthreads();
  // flush xn (bf16) for k6: [b][c][l], coalesced over l
  for (int i = tid; i < CC * TLV; i += 256) {
    int c = i / TLV, j2 = i - c * TLV;            // col j2+3, l = l0+j2
    int l = l0 + j2;
    if (l < LL) xn_ws[((size_t)(b * CC + c)) * LL + l] = f2bf(xnT[(j2 + 3) * 132 + c]);
  }
  int g = tid >> 6, j = tid & 63;
  // read own column's g-slice to regs (before barrier; xnT is overwritten by xiS after)
  float xr[32];
  {
    const float4* xp4 = (const float4*)&xnT[j * 132 + g * DM];
#pragma unroll
    for (int q = 0; q < 8; q++) {
      float4 v = xp4[q];
      xr[4 * q] = v.x; xr[4 * q + 1] = v.y; xr[4 * q + 2] = v.z; xr[4 * q + 3] = v.w;
    }
  }
  __syncthreads();                                 // all xnT reads (flush + xr) done
  float acc[DI];
#pragma unroll
  for (int d = 0; d < DI; d++) {                   // xi matvec; weights wave-uniform -> s_load
    const float* w = in_proj_w + d * DM;
    float a = 0.f;
#pragma unroll
    for (int r = 0; r < 32; r++) a = fmaf(xr[r], w[r], a);
    acc[d] = a;
  }
  if (l0 - 3 + j < 0) {                            // cols before l=0 contribute zero
#pragma unroll
    for (int d = 0; d < DI; d++) acc[d] = 0.f;
  }
  {
    uint2* xo = (uint2*)&xiS[(g * 64 + j) * 68];   // row stride 136B: 8B-aligned, conflict-free
#pragma unroll
    for (int k = 0; k < 16; k++) {
      uint2 p;
      p.x = pack2(acc[4 * k + 0], acc[4 * k + 1]);
      p.y = pack2(acc[4 * k + 2], acc[4 * k + 3]);
      xo[k] = p;
    }
  }
  __syncthreads();
  // phase B: conv along columns; thread = (g, d)
  int d = j;
  float cw0 = conv_w[d * 4 + 0], cw1 = conv_w[d * 4 + 1];
  float cw2 = conv_w[d * 4 + 2], cw3 = conv_w[d * 4 + 3];
  float cb = conv_b[d];
  bf* uo = u_ws + (size_t)(g * BB + b) * LL * DI + d;
  float x3 = 0.f, x2 = 0.f, x1 = 0.f, x0 = 0.f;
  for (int jj = 0; jj < 64; jj++) {
    float xi = us2f(xiS[(g * 64 + jj) * 68 + d]);  // lanes d consecutive -> 2-way (free)
    x3 = x2; x2 = x1; x1 = x0; x0 = xi;
    int l = l0 + jj - 3;
    if (jj >= 3 && l < LL) {
      float pre = x3 * cw0 + x2 * cw1 + x1 * cw2 + x0 * cw3 + cb;
      float uu = pre * sigmoidf_(pre);
      uo[(size_t)l * DI] = f2bf(uu);               // coalesced 128B
    }
  }
}

// ---------------- K2: x_proj + dt_proj + softplus -> delta, B, C (bf16) ----------------
// grid: 1024 blocks, 256 threads; one position per thread; register-blocked; IO via LDS, coalesced.
__global__ __launch_bounds__(256) void k2_xproj(
    const bf* __restrict__ u_ws, const float* __restrict__ x_proj_w,
    const float* __restrict__ dt_proj_w, const float* __restrict__ dt_proj_b,
    bf* __restrict__ delta_ws, bf* __restrict__ Bws, bf* __restrict__ Cws) {
  __shared__ unsigned uS[256 * 33];      // 256 rows x 32 dwords, stride 33 -> conflict-free
  __shared__ unsigned bcS[2][256 * 9];   // B/C staging, stride 9
  int tid = threadIdx.x;
  size_t pos0 = (size_t)blockIdx.x * 256;
  const unsigned* src = (const unsigned*)u_ws + pos0 * 32;
#pragma unroll
  for (int k = 0; k < 32; k++) {         // coalesced fill
    int idx = tid + k * 256;
    uS[(idx >> 5) * 33 + (idx & 31)] = src[idx];
  }
  __syncthreads();
  float xdb[34];
#pragma unroll
  for (int e = 0; e < 34; e++) xdb[e] = 0.f;
#pragma unroll
  for (int c2 = 0; c2 < 4; c2++) {       // register-blocked: 16 u-values live at a time
    float f[16];
#pragma unroll
    for (int k = 0; k < 8; k++) {
      unsigned v = uS[tid * 33 + c2 * 8 + k];
      f[2 * k] = blo(v); f[2 * k + 1] = bhi(v);
    }
#pragma unroll
    for (int e = 0; e < 34; e++) {       // weights wave-uniform -> s_load
      const float* w = x_proj_w + e * DI + c2 * 16;
      float a = xdb[e];
#pragma unroll
      for (int i = 0; i < 16; i++) a = fmaf(f[i], w[i], a);
      xdb[e] = a;
    }
  }
#pragma unroll
  for (int n = 0; n < 8; n++) bcS[0][tid * 9 + n] = pack2(xdb[2 + 2 * n], xdb[3 + 2 * n]);
#pragma unroll
  for (int n = 0; n < 8; n++) bcS[1][tid * 9 + n] = pack2(xdb[18 + 2 * n], xdb[19 + 2 * n]);
  float dt0 = xdb[0], dt1 = xdb[1];
  for (int d2 = 0; d2 < 32; d2++) {      // delta into own uS row (thread-owned, no barrier)
    float r0 = softplusf_(dt0 * dt_proj_w[4 * d2 + 0] + dt1 * dt_proj_w[4 * d2 + 1] + dt_proj_b[2 * d2]);
    float r1 = softplusf_(dt0 * dt_proj_w[4 * d2 + 2] + dt1 * dt_proj_w[4 * d2 + 3] + dt_proj_b[2 * d2 + 1]);
    uS[tid * 33 + d2] = pack2(r0, r1);
  }
  __syncthreads();
  unsigned* ddst = (unsigned*)delta_ws + pos0 * 32;
#pragma unroll
  for (int k = 0; k < 32; k++) {
    int idx = tid + k * 256;
    ddst[idx] = uS[(idx >> 5) * 33 + (idx & 31)];
  }
  unsigned* bdst = (unsigned*)Bws + pos0 * 8;
  unsigned* cdst = (unsigned*)Cws + pos0 * 8;
#pragma unroll
  for (int k = 0; k < 8; k++) {
    int idx = tid + k * 256;
    bdst[idx] = bcS[0][(idx >> 3) * 9 + (idx & 7)];
  }
#pragma unroll
  for (int k = 0; k < 8; k++) {
    int idx = tid + k * 256;
    cdst[idx] = bcS[1][(idx >> 3) * 9 + (idx & 7)];
  }
}

// A2[n] == (n+1)*A2[0] for this problem's A = arange(1..16); guarded fast path.
__device__ __forceinline__ bool ladder_ok(const float* A2) {
  bool ok = true;
#pragma unroll
  for (int n = 0; n < DSN; n++) {
    float r = A2[n] / A2[0];
    ok = ok && (fabsf(r - (float)(n + 1)) < 1e-3f);
  }
  return ok;
}

// ---------------- K3: scan pass A — local states + chunk transition products ----------------
// grid: GG*NC = 4096 blocks, 64 threads (1 wave, lane = d). 16 waves/CU.
__global__ __launch_bounds__(64) void k3_scanA(
    const bf* __restrict__ delta_ws, const bf* __restrict__ u_ws, const bf* __restrict__ Bws,
    const float* __restrict__ A_log, float* __restrict__ hloc, float* __restrict__ Aprod) {
  int s = blockIdx.x >> 6, chunk = blockIdx.x & (NC - 1);
  int d = threadIdx.x;
  float A2[DSN];
#pragma unroll
  for (int n = 0; n < DSN; n++)
    A2[n] = -__expf(A_log[d * DSN + n]) * 1.44269504088896f;  // A * log2(e)
  bool ok = ladder_ok(A2);
  float h[DSN];
#pragma unroll
  for (int n = 0; n < DSN; n++) h[n] = 0.f;
  float ssum = 0.f;
  size_t base = (size_t)s * LL + (size_t)chunk * CL;
  const unsigned short* dp = (const unsigned short*)delta_ws + base * DI + d;
  const unsigned short* up = (const unsigned short*)u_ws + base * DI + d;
  const uint4* bp = (const uint4*)(Bws + base * DSN);
  if (ok) {
    float a0 = A2[0];
    for (int t = 0; t < CL; t++) {
      float delta = us2f(dp[(size_t)t * DI]);
      float uu    = us2f(up[(size_t)t * DI]);
      float Bv[16];
      unpack8(bp[t * 2], Bv); unpack8(bp[t * 2 + 1], Bv + 8);
      float du = delta * uu;
      ssum += delta;
      float E = EXP2F(delta * a0);
      float e = E;
#pragma unroll
      for (int n = 0; n < DSN; n++) {
        h[n] = fmaf(h[n], e, du * Bv[n]);
        e *= E;
      }
    }
  } else {
    for (int t = 0; t < CL; t++) {
      float delta = us2f(dp[(size_t)t * DI]);
      float uu    = us2f(up[(size_t)t * DI]);
      float Bv[16];
      unpack8(bp[t * 2], Bv); unpack8(bp[t * 2 + 1], Bv + 8);
      float du = delta * uu;
      ssum += delta;
#pragma unroll
      for (int n = 0; n < DSN; n++) {
        float e = EXP2F(delta * A2[n]);
        h[n] = fmaf(h[n], e, du * Bv[n]);
      }
    }
  }
  size_t ob = (size_t)blockIdx.x * (DSN * DI) + d;
#pragma unroll
  for (int n = 0; n < DSN; n++) {
    hloc[ob + n * DI] = h[n];
    Aprod[ob + n * DI] = EXP2F(A2[n] * ssum);
  }
}

// ---------------- K4: sequential cross-chunk combine -> per-chunk initial states ----------------
// grid: GG blocks, 64 threads. hin ALIASES hloc (reads precede the write per address, same thread).
__global__ __launch_bounds__(64) void k4_combine(
    const float* __restrict__ Aprod, float* hloc_hin) {
  int s = blockIdx.x, d = threadIdx.x;
  float h[DSN];
#pragma unroll
  for (int n = 0; n < DSN; n++) h[n] = 0.f;
  for (int k = 0; k < NC; k++) {
    size_t base = (size_t)(s * NC + k) * (DSN * DI) + d;
#pragma unroll
    for (int n = 0; n < DSN; n++) {
      float hl = hloc_hin[base + n * DI];
      float ap = Aprod[base + n * DI];
      hloc_hin[base + n * DI] = h[n];             // write h_in over h_loc
      h[n] = fmaf(h[n], ap, hl);
    }
  }
}

// ---------------- K5: scan pass C — replay with h_in, emit y2 = y + u*D (bf16, in-place over delta) ----------------
// grid: GG*NC = 4096 blocks, 64 threads.
__global__ __launch_bounds__(64) void k5_scanC(
    bf* dy, const bf* __restrict__ u_ws,
    const bf* __restrict__ Bws, const bf* __restrict__ Cws,
    const float* __restrict__ A_log, const float* __restrict__ Dw,
    const float* __restrict__ hin) {
  int s = blockIdx.x >> 6, chunk = blockIdx.x & (NC - 1);
  int d = threadIdx.x;
  float A2[DSN];
#pragma unroll
  for (int n = 0; n < DSN; n++)
    A2[n] = -__expf(A_log[d * DSN + n]) * 1.44269504088896f;
  bool ok = ladder_ok(A2);
  float Dd = Dw[d];
  float h[DSN];
  size_t hb = (size_t)blockIdx.x * (DSN * DI) + d;
#pragma unroll
  for (int n = 0; n < DSN; n++) h[n] = hin[hb + n * DI];
  size_t base = (size_t)s * LL + (size_t)chunk * CL;
  unsigned short* dyp = (unsigned short*)dy + base * DI + d;
  const unsigned short* up = (const unsigned short*)u_ws + base * DI + d;
  const uint4* bp = (const uint4*)(Bws + base * DSN);
  const uint4* cp = (const uint4*)(Cws + base * DSN);
  if (ok) {
    float a0 = A2[0];
    for (int t = 0; t < CL; t++) {
      float delta = us2f(dyp[(size_t)t * DI]);
      float uu    = us2f(up[(size_t)t * DI]);
      float Bv[16], Cv[16];
      unpack8(bp[t * 2], Bv); unpack8(bp[t * 2 + 1], Bv + 8);
      unpack8(cp[t * 2], Cv); unpack8(cp[t * 2 + 1], Cv + 8);
      float du = delta * uu;
      float y = 0.f;
      float E = EXP2F(delta * a0);
      float e = E;
#pragma unroll
      for (int n = 0; n < DSN; n++) {
        h[n] = fmaf(h[n], e, du * Bv[n]);
        y = fmaf(h[n], Cv[n], y);
        e *= E;
      }
      bf r = f2bf(y + uu * Dd);
      dyp[(size_t)t * DI] = *(unsigned short*)&r;
    }
  } else {
    for (int t = 0; t < CL; t++) {
      float delta = us2f(dyp[(size_t)t * DI]);
      float uu    = us2f(up[(size_t)t * DI]);
      float Bv[16], Cv[16];
      unpack8(bp[t * 2], Bv); unpack8(bp[t * 2 + 1], Bv + 8);
      unpack8(cp[t * 2], Cv); unpack8(cp[t * 2 + 1], Cv + 8);
      float du = delta * uu;
      float y = 0.f;
#pragma unroll
      for (int n = 0; n < DSN; n++) {
        float e = EXP2F(delta * A2[n]);
        h[n] = fmaf(h[n], e, du * Bv[n]);
        y = fmaf(h[n], Cv[n], y);
      }
      bf r = f2bf(y + uu * Dd);
      dyp[(size_t)t * DI] = *(unsigned short*)&r;
    }
  }
}

// ---------------- K6: z-gate + out_proj + residual -> output (fp32). Reads xn(bf16), y2(bf16). ----------------
// grid: BB * (LL/TL) = 1024 blocks, 256 threads; thread = (g, column j). All acc loops unrolled
// (constant indices) so acc[] stays in VGPRs — no scratch.
__global__ __launch_bounds__(256) void k6_final(
    const bf* __restrict__ xn_ws, const float* __restrict__ in_proj_w,
    const float* __restrict__ out_proj_w, const bf* __restrict__ y2ws,
    float* __restrict__ out) {
  __shared__ unsigned short xnS[CC][66];   // row stride 33 dwords -> conflict-free
  __shared__ unsigned y2S[4][64 * 33];     // per-g: 64 rows x 32 dwords, stride 33
  int b = blockIdx.x >> 6;
  int tile = blockIdx.x & 63;
  int l0 = tile * TL;
  int tid = threadIdx.x;
  const unsigned* xsrc = (const unsigned*)xn_ws;
#pragma unroll
  for (int k = 0; k < 16; k++) {           // xn tile: coalesced
    int idx = tid + k * 256;
    int c = idx >> 5, dw = idx & 31;
    ((unsigned*)&xnS[c][0])[dw] = xsrc[(((size_t)(b * CC + c)) * LL + l0) / 2 + dw];
  }
#pragma unroll
  for (int k = 0; k < 32; k++) {           // y2 tile: coalesced per g-chunk
    int idx = tid + k * 256;
    int g = idx >> 11, rem = idx & 2047;
    const unsigned* ysrc = (const unsigned*)(y2ws + (((size_t)(g * BB + b)) * LL + l0) * DI);
    y2S[g][(rem >> 5) * 33 + (rem & 31)] = ysrc[rem];
  }
  __syncthreads();
  int j = tid & 63, g = tid >> 6;
  float xcol[32];
#pragma unroll
  for (int r = 0; r < 32; r++)
    xcol[r] = us2f(xnS[g * 32 + r][j]);
  float acc[DI];
#pragma unroll
  for (int d = 0; d < DI; d++) {           // z projection — UNROLLED: acc stays in VGPRs
    const float* w = in_proj_w + (DI + d) * DM;
    float a = 0.f;
#pragma unroll
    for (int r = 0; r < 32; r++) a = fmaf(xcol[r], w[r], a);
    acc[d] = a;
  }
  const unsigned* yrow = &y2S[g][j * 33];
#pragma unroll
  for (int k = 0; k < 32; k++) {           // gate: y3 = y2 * silu(z)
    unsigned v = yrow[k];
    float z0 = acc[2 * k], z1 = acc[2 * k + 1];
    acc[2 * k]     = blo(v) * (z0 * sigmoidf_(z0));
    acc[2 * k + 1] = bhi(v) * (z1 * sigmoidf_(z1));
  }
  float* ob = out + ((size_t)(b * CC + g * DM)) * LL + l0 + j;
  for (int jj = 0; jj < DM; jj++) {        // out_proj + residual (inner unrolled: const acc idx)
    const float* w = out_proj_w + jj * DI;
    float a = us2f(xnS[g * 32 + jj][j]);   // residual xn
#pragma unroll
    for (int d = 0; d < DI; d++) a = fmaf(acc[d], w[d], a);
    ob[(size_t)jj * LL] = a;               // coalesced 256B
  }
}

extern "C" void kernel_launch(void* const* d_in, const int* in_sizes, int n_in,
                              void* d_out, int out_size, void* d_ws, size_t ws_size,
                              hipStream_t stream) {
  const float* input     = (const float*)d_in[0];
  const float* ln_g      = (const float*)d_in[1];
  const float* ln_b      = (const float*)d_in[2];
  const float* in_proj_w = (const float*)d_in[3];
  const float* conv_w    = (const float*)d_in[4];
  const float* conv_b    = (const float*)d_in[5];
  const float* x_proj_w  = (const float*)d_in[6];
  const float* dt_proj_w = (const float*)d_in[7];
  const float* dt_proj_b = (const float*)d_in[8];
  const float* A_log     = (const float*)d_in[9];
  const float* Dw        = (const float*)d_in[10];
  const float* out_proj_w= (const float*)d_in[11];
  float* out = (float*)d_out;

  char* ws = (char*)d_ws;
  bf*    u_ws     = (bf*)(ws);                    // 32 MiB
  bf*    delta_ws = (bf*)(ws + 33554432);         // 32 MiB (y2 aliases after k5)
  bf*    Bws      = (bf*)(ws + 67108864);         // 8 MiB
  bf*    Cws      = (bf*)(ws + 75497472);         // 8 MiB
  bf*    xn_ws    = (bf*)(ws + 83886080);         // 16 MiB
  float* hloc     = (float*)(ws + 100663296);     // 16 MiB (hin aliases)
  float* Aprod    = (float*)(ws + 117440512);     // 16 MiB  -> total 128 MiB
  (void)in_sizes; (void)n_in; (void)out_size; (void)ws_size;

  hipLaunchKernelGGL(k1_ln_conv, dim3(BB * NT), dim3(256), 0, stream,
                     input, ln_g, ln_b, in_proj_w, conv_w, conv_b, u_ws, xn_ws);
  hipLaunchKernelGGL(k2_xproj, dim3(1024), dim3(256), 0, stream,
                     u_ws, x_proj_w, dt_proj_w, dt_proj_b, delta_ws, Bws, Cws);
  hipLaunchKernelGGL(k3_scanA, dim3(GG * NC), dim3(64), 0, stream,
                     delta_ws, u_ws, Bws, A_log, hloc, Aprod);
  hipLaunchKernelGGL(k4_combine, dim3(GG), dim3(64), 0, stream,
                     Aprod, hloc);
  hipLaunchKernelGGL(k5_scanC, dim3(GG * NC), dim3(64), 0, stream,
                     delta_ws, u_ws, Bws, Cws, A_log, Dw, hloc);
  hipLaunchKernelGGL(k6_final, dim3(1024), dim3(256), 0, stream,
                     xn_ws, in_proj_w, out_proj_w, delta_ws, out);
}

// Round 6
// 488.288 us; speedup vs baseline: 1.2868x; 1.2868x over previous
//
#include <hip/hip_runtime.h>
#include <hip/hip_bf16.h>
#include <math.h>

typedef __hip_bfloat16 bf;

#define BB   16     // batch
#define CC   128    // channels
#define LL   4096   // H*W
#define DM   32     // d_model per chunk
#define DI   64     // d_inner
#define DSN  16     // d_state
#define GG   64     // 4 * BB sequences
#define NC   64     // scan chunks
#define CL   64     // LL / NC
#define TLV  61     // valid output columns per k1 tile (64 loaded, 3 head)
#define NT   68     // ceil(LL / TLV)
#define TL   64     // l-tile for k6
#define XS   133    // xnT row stride in dwords (odd -> conflict-free lane-strided b32)
#define YS   35     // xiS row stride in dwords (70 shorts, odd dwords)

__device__ __forceinline__ float bf2f(bf x) { return __bfloat162float(x); }
__device__ __forceinline__ bf f2bf(float x) { return __float2bfloat16(x); }
__device__ __forceinline__ float blo(unsigned v) { return __uint_as_float(v << 16); }
__device__ __forceinline__ float bhi(unsigned v) { return __uint_as_float(v & 0xffff0000u); }
__device__ __forceinline__ float us2f(unsigned short v) { return __uint_as_float((unsigned)v << 16); }
__device__ __forceinline__ unsigned pack2(float a, float b) {
  bf ba = f2bf(a), bb = f2bf(b);
  unsigned short ua = *(unsigned short*)&ba, ub = *(unsigned short*)&bb;
  return (unsigned)ua | ((unsigned)ub << 16);
}

#if __has_builtin(__builtin_amdgcn_exp2f)
#define EXP2F(x) __builtin_amdgcn_exp2f(x)
#else
#define EXP2F(x) exp2f(x)
#endif

__device__ __forceinline__ float sigmoidf_(float x) { return 1.0f / (1.0f + __expf(-x)); }
__device__ __forceinline__ float softplusf_(float x) {
  return fmaxf(x, 0.0f) + log1pf(__expf(-fabsf(x)));
}
__device__ __forceinline__ void unpack8(uint4 v, float* o) {
  o[0] = blo(v.x); o[1] = bhi(v.x); o[2] = blo(v.y); o[3] = bhi(v.y);
  o[4] = blo(v.z); o[5] = bhi(v.z); o[6] = blo(v.w); o[7] = bhi(v.w);
}

// ---------------- K1: layernorm + in_proj(xi) + causal conv + silu -> u (bf16), xn (bf16) ----------------
// grid: BB * NT = 1088 blocks, 256 threads. 64 cols loaded (l0-3 .. l0+60), 61 outputs.
// Phase A: thread=(g,col) computes xi in 4 chunks of 16 outputs (live regs ~60, no spill),
// writes bf16 xi to LDS. Phase B: thread=(g,d) runs the conv. All LDS strides odd -> conflict-free.
__global__ __launch_bounds__(256, 4) void k1_ln_conv(
    const float* __restrict__ input, const float* __restrict__ ln_g, const float* __restrict__ ln_b,
    const float* __restrict__ in_proj_w, const float* __restrict__ conv_w, const float* __restrict__ conv_b,
    bf* __restrict__ u_ws, bf* __restrict__ xn_ws) {
  __shared__ unsigned ldsbuf[8960];               // union: xnT fp32 64 rows x 133 dw (34048B) / xiS bf16 256 rows x 35 dw (35840B)
  __shared__ float mu_s[64], rs_s[64];
  float* xnT = (float*)ldsbuf;
  unsigned short* xiS = (unsigned short*)ldsbuf;
  int b = blockIdx.x / NT;
  int tile = blockIdx.x - b * NT;
  int l0 = tile * TLV;
  int tid = threadIdx.x;
  const float* inb = input + (size_t)b * CC * LL;
#pragma unroll
  for (int k = 0; k < 32; k++) {                  // fill 64 cols x 128 ch; coalesced global, stride-133 LDS
    int i = tid + k * 256;
    int j = i & 63, c = i >> 6;
    int l = l0 - 3 + j;
    xnT[j * XS + c] = (l >= 0 && l < LL) ? inb[c * LL + l] : 0.0f;
  }
  __syncthreads();
  if (tid < 64) {
    float s = 0.f, s2 = 0.f;
    for (int c = 0; c < CC; c++) { float v = xnT[tid * XS + c]; s += v; s2 = fmaf(v, v, s2); }
    float mu = s * (1.0f / CC);
    float var = s2 * (1.0f / CC) - mu * mu;
    mu_s[tid] = mu;
    rs_s[tid] = rsqrtf(var + 1e-5f);
  }
  __syncthreads();
#pragma unroll
  for (int k = 0; k < 32; k++) {                  // normalize; c wave-uniform -> scalar ln_g/ln_b
    int i = tid + k * 256;
    int j = i & 63, c = i >> 6;
    xnT[j * XS + c] = (xnT[j * XS + c] - mu_s[j]) * rs_s[j] * ln_g[c] + ln_b[c];
  }
  __syncthreads();
  // flush xn (bf16) for k6: [b][c][l], coalesced over l
  for (int i = tid; i < CC * TLV; i += 256) {
    int c = i / TLV, j2 = i - c * TLV;
    int l = l0 + j2;
    if (l < LL) xn_ws[((size_t)(b * CC + c)) * LL + l] = f2bf(xnT[(j2 + 3) * XS + c]);
  }
  int g = tid >> 6, j = tid & 63;
  float xr[32];
#pragma unroll
  for (int r = 0; r < 32; r++) xr[r] = xnT[j * XS + g * DM + r];  // lane-stride 133 dw -> conflict-free
  bool zero_col = (l0 - 3 + j < 0);
  __syncthreads();                                 // all xnT reads done; buffer becomes xiS
#pragma unroll
  for (int c2 = 0; c2 < 4; c2++) {                 // 16 outputs per chunk -> acc stays in VGPRs
    float acc[16];
#pragma unroll
    for (int dd = 0; dd < 16; dd++) {              // weights wave-uniform -> s_load
      const float* w = in_proj_w + (c2 * 16 + dd) * DM;
      float a = 0.f;
#pragma unroll
      for (int r = 0; r < 32; r++) a = fmaf(xr[r], w[r], a);
      acc[dd] = zero_col ? 0.f : a;
    }
    unsigned* xo = (unsigned*)&ldsbuf[(g * 64 + j) * YS + c2 * 8];
#pragma unroll
    for (int k = 0; k < 8; k++)                    // b32 writes, lane row-stride 35 dw -> conflict-free
      xo[k] = pack2(acc[2 * k], acc[2 * k + 1]);
  }
  __syncthreads();
  // phase B: conv along columns; thread = (g, d)
  int d = j;
  float cw0 = conv_w[d * 4 + 0], cw1 = conv_w[d * 4 + 1];
  float cw2 = conv_w[d * 4 + 2], cw3 = conv_w[d * 4 + 3];
  float cb = conv_b[d];
  bf* uo = u_ws + (size_t)(g * BB + b) * LL * DI + d;
  float x3 = 0.f, x2 = 0.f, x1 = 0.f, x0 = 0.f;
  for (int jj = 0; jj < 64; jj++) {
    float xi = us2f(xiS[(g * 64 + jj) * (2 * YS) + d]);  // row uniform, d consecutive -> broadcast pairs, conflict-free
    x3 = x2; x2 = x1; x1 = x0; x0 = xi;
    int l = l0 + jj - 3;
    if (jj >= 3 && l < LL) {
      float pre = x3 * cw0 + x2 * cw1 + x1 * cw2 + x0 * cw3 + cb;
      float uu = pre * sigmoidf_(pre);
      uo[(size_t)l * DI] = f2bf(uu);               // coalesced 128B
    }
  }
}

// ---------------- K2: x_proj + dt_proj + softplus -> delta, B, C (bf16) ----------------
// grid: 1024 blocks, 256 threads; one position per thread; register-blocked; IO via LDS, coalesced.
__global__ __launch_bounds__(256) void k2_xproj(
    const bf* __restrict__ u_ws, const float* __restrict__ x_proj_w,
    const float* __restrict__ dt_proj_w, const float* __restrict__ dt_proj_b,
    bf* __restrict__ delta_ws, bf* __restrict__ Bws, bf* __restrict__ Cws) {
  __shared__ unsigned uS[256 * 33];      // 256 rows x 32 dwords, stride 33 -> conflict-free
  __shared__ unsigned bcS[2][256 * 9];   // B/C staging, stride 9
  int tid = threadIdx.x;
  size_t pos0 = (size_t)blockIdx.x * 256;
  const unsigned* src = (const unsigned*)u_ws + pos0 * 32;
#pragma unroll
  for (int k = 0; k < 32; k++) {         // coalesced fill
    int idx = tid + k * 256;
    uS[(idx >> 5) * 33 + (idx & 31)] = src[idx];
  }
  __syncthreads();
  float xdb[34];
#pragma unroll
  for (int e = 0; e < 34; e++) xdb[e] = 0.f;
#pragma unroll
  for (int c2 = 0; c2 < 4; c2++) {       // register-blocked: 16 u-values live at a time
    float f[16];
#pragma unroll
    for (int k = 0; k < 8; k++) {
      unsigned v = uS[tid * 33 + c2 * 8 + k];
      f[2 * k] = blo(v); f[2 * k + 1] = bhi(v);
    }
#pragma unroll
    for (int e = 0; e < 34; e++) {       // weights wave-uniform -> s_load
      const float* w = x_proj_w + e * DI + c2 * 16;
      float a = xdb[e];
#pragma unroll
      for (int i = 0; i < 16; i++) a = fmaf(f[i], w[i], a);
      xdb[e] = a;
    }
  }
#pragma unroll
  for (int n = 0; n < 8; n++) bcS[0][tid * 9 + n] = pack2(xdb[2 + 2 * n], xdb[3 + 2 * n]);
#pragma unroll
  for (int n = 0; n < 8; n++) bcS[1][tid * 9 + n] = pack2(xdb[18 + 2 * n], xdb[19 + 2 * n]);
  float dt0 = xdb[0], dt1 = xdb[1];
  for (int d2 = 0; d2 < 32; d2++) {      // delta into own uS row (thread-owned, no barrier)
    float r0 = softplusf_(dt0 * dt_proj_w[4 * d2 + 0] + dt1 * dt_proj_w[4 * d2 + 1] + dt_proj_b[2 * d2]);
    float r1 = softplusf_(dt0 * dt_proj_w[4 * d2 + 2] + dt1 * dt_proj_w[4 * d2 + 3] + dt_proj_b[2 * d2 + 1]);
    uS[tid * 33 + d2] = pack2(r0, r1);
  }
  __syncthreads();
  unsigned* ddst = (unsigned*)delta_ws + pos0 * 32;
#pragma unroll
  for (int k = 0; k < 32; k++) {
    int idx = tid + k * 256;
    ddst[idx] = uS[(idx >> 5) * 33 + (idx & 31)];
  }
  unsigned* bdst = (unsigned*)Bws + pos0 * 8;
  unsigned* cdst = (unsigned*)Cws + pos0 * 8;
#pragma unroll
  for (int k = 0; k < 8; k++) {
    int idx = tid + k * 256;
    bdst[idx] = bcS[0][(idx >> 3) * 9 + (idx & 7)];
  }
#pragma unroll
  for (int k = 0; k < 8; k++) {
    int idx = tid + k * 256;
    cdst[idx] = bcS[1][(idx >> 3) * 9 + (idx & 7)];
  }
}

// A2[n] == (n+1)*A2[0] for this problem's A = arange(1..16); guarded fast path.
__device__ __forceinline__ bool ladder_ok(const float* A2) {
  bool ok = true;
#pragma unroll
  for (int n = 0; n < DSN; n++) {
    float r = A2[n] / A2[0];
    ok = ok && (fabsf(r - (float)(n + 1)) < 1e-3f);
  }
  return ok;
}

// ---------------- K3: scan pass A — local states + chunk transition products ----------------
// grid: GG*NC = 4096 blocks, 64 threads (1 wave, lane = d). 16 waves/CU.
__global__ __launch_bounds__(64) void k3_scanA(
    const bf* __restrict__ delta_ws, const bf* __restrict__ u_ws, const bf* __restrict__ Bws,
    const float* __restrict__ A_log, float* __restrict__ hloc, float* __restrict__ Aprod) {
  int s = blockIdx.x >> 6, chunk = blockIdx.x & (NC - 1);
  int d = threadIdx.x;
  float A2[DSN];
#pragma unroll
  for (int n = 0; n < DSN; n++)
    A2[n] = -__expf(A_log[d * DSN + n]) * 1.44269504088896f;  // A * log2(e)
  bool ok = ladder_ok(A2);
  float h[DSN];
#pragma unroll
  for (int n = 0; n < DSN; n++) h[n] = 0.f;
  float ssum = 0.f;
  size_t base = (size_t)s * LL + (size_t)chunk * CL;
  const unsigned short* dp = (const unsigned short*)delta_ws + base * DI + d;
  const unsigned short* up = (const unsigned short*)u_ws + base * DI + d;
  const uint4* bp = (const uint4*)(Bws + base * DSN);
  if (ok) {
    float a0 = A2[0];
    for (int t = 0; t < CL; t++) {
      float delta = us2f(dp[(size_t)t * DI]);
      float uu    = us2f(up[(size_t)t * DI]);
      float Bv[16];
      unpack8(bp[t * 2], Bv); unpack8(bp[t * 2 + 1], Bv + 8);
      float du = delta * uu;
      ssum += delta;
      float E = EXP2F(delta * a0);
      float e = E;
#pragma unroll
      for (int n = 0; n < DSN; n++) {
        h[n] = fmaf(h[n], e, du * Bv[n]);
        e *= E;
      }
    }
  } else {
    for (int t = 0; t < CL; t++) {
      float delta = us2f(dp[(size_t)t * DI]);
      float uu    = us2f(up[(size_t)t * DI]);
      float Bv[16];
      unpack8(bp[t * 2], Bv); unpack8(bp[t * 2 + 1], Bv + 8);
      float du = delta * uu;
      ssum += delta;
#pragma unroll
      for (int n = 0; n < DSN; n++) {
        float e = EXP2F(delta * A2[n]);
        h[n] = fmaf(h[n], e, du * Bv[n]);
      }
    }
  }
  size_t ob = (size_t)blockIdx.x * (DSN * DI) + d;
#pragma unroll
  for (int n = 0; n < DSN; n++) {
    hloc[ob + n * DI] = h[n];
    Aprod[ob + n * DI] = EXP2F(A2[n] * ssum);
  }
}

// ---------------- K4: sequential cross-chunk combine -> per-chunk initial states ----------------
// grid: GG blocks, 64 threads. hin ALIASES hloc (read precedes write per address, same thread).
__global__ __launch_bounds__(64) void k4_combine(
    const float* __restrict__ Aprod, float* hloc_hin) {
  int s = blockIdx.x, d = threadIdx.x;
  float h[DSN];
#pragma unroll
  for (int n = 0; n < DSN; n++) h[n] = 0.f;
  for (int k = 0; k < NC; k++) {
    size_t base = (size_t)(s * NC + k) * (DSN * DI) + d;
#pragma unroll
    for (int n = 0; n < DSN; n++) {
      float hl = hloc_hin[base + n * DI];
      float ap = Aprod[base + n * DI];
      hloc_hin[base + n * DI] = h[n];             // write h_in over h_loc
      h[n] = fmaf(h[n], ap, hl);
    }
  }
}

// ---------------- K5: scan pass C — replay with h_in, emit y2 = y + u*D (bf16, in-place over delta) ----------------
// grid: GG*NC = 4096 blocks, 64 threads.
__global__ __launch_bounds__(64) void k5_scanC(
    bf* dy, const bf* __restrict__ u_ws,
    const bf* __restrict__ Bws, const bf* __restrict__ Cws,
    const float* __restrict__ A_log, const float* __restrict__ Dw,
    const float* __restrict__ hin) {
  int s = blockIdx.x >> 6, chunk = blockIdx.x & (NC - 1);
  int d = threadIdx.x;
  float A2[DSN];
#pragma unroll
  for (int n = 0; n < DSN; n++)
    A2[n] = -__expf(A_log[d * DSN + n]) * 1.44269504088896f;
  bool ok = ladder_ok(A2);
  float Dd = Dw[d];
  float h[DSN];
  size_t hb = (size_t)blockIdx.x * (DSN * DI) + d;
#pragma unroll
  for (int n = 0; n < DSN; n++) h[n] = hin[hb + n * DI];
  size_t base = (size_t)s * LL + (size_t)chunk * CL;
  unsigned short* dyp = (unsigned short*)dy + base * DI + d;
  const unsigned short* up = (const unsigned short*)u_ws + base * DI + d;
  const uint4* bp = (const uint4*)(Bws + base * DSN);
  const uint4* cp = (const uint4*)(Cws + base * DSN);
  if (ok) {
    float a0 = A2[0];
    for (int t = 0; t < CL; t++) {
      float delta = us2f(dyp[(size_t)t * DI]);
      float uu    = us2f(up[(size_t)t * DI]);
      float Bv[16], Cv[16];
      unpack8(bp[t * 2], Bv); unpack8(bp[t * 2 + 1], Bv + 8);
      unpack8(cp[t * 2], Cv); unpack8(cp[t * 2 + 1], Cv + 8);
      float du = delta * uu;
      float y = 0.f;
      float E = EXP2F(delta * a0);
      float e = E;
#pragma unroll
      for (int n = 0; n < DSN; n++) {
        h[n] = fmaf(h[n], e, du * Bv[n]);
        y = fmaf(h[n], Cv[n], y);
        e *= E;
      }
      bf r = f2bf(y + uu * Dd);
      dyp[(size_t)t * DI] = *(unsigned short*)&r;
    }
  } else {
    for (int t = 0; t < CL; t++) {
      float delta = us2f(dyp[(size_t)t * DI]);
      float uu    = us2f(up[(size_t)t * DI]);
      float Bv[16], Cv[16];
      unpack8(bp[t * 2], Bv); unpack8(bp[t * 2 + 1], Bv + 8);
      unpack8(cp[t * 2], Cv); unpack8(cp[t * 2 + 1], Cv + 8);
      float du = delta * uu;
      float y = 0.f;
#pragma unroll
      for (int n = 0; n < DSN; n++) {
        float e = EXP2F(delta * A2[n]);
        h[n] = fmaf(h[n], e, du * Bv[n]);
        y = fmaf(h[n], Cv[n], y);
      }
      bf r = f2bf(y + uu * Dd);
      dyp[(size_t)t * DI] = *(unsigned short*)&r;
    }
  }
}

// ---------------- K6: z-gate + out_proj + residual -> output (fp32). Reads xn(bf16), y2(bf16). ----------------
// grid: BB * (LL/TL) = 1024 blocks, 256 threads; thread = (g, column j). launch_bounds(256,3):
// VGPR cap ~170 so acc[64]+xcol[32] registerize (no scratch); LDS limits to 3 blocks/CU anyway.
__global__ __launch_bounds__(256, 3) void k6_final(
    const bf* __restrict__ xn_ws, const float* __restrict__ in_proj_w,
    const float* __restrict__ out_proj_w, const bf* __restrict__ y2ws,
    float* __restrict__ out) {
  __shared__ unsigned short xnS[CC][66];   // row stride 33 dwords -> conflict-free
  __shared__ unsigned y2S[4][64 * 33];     // per-g: 64 rows x 32 dwords, stride 33
  int b = blockIdx.x >> 6;
  int tile = blockIdx.x & 63;
  int l0 = tile * TL;
  int tid = threadIdx.x;
  const unsigned* xsrc = (const unsigned*)xn_ws;
#pragma unroll
  for (int k = 0; k < 16; k++) {           // xn tile: coalesced
    int idx = tid + k * 256;
    int c = idx >> 5, dw = idx & 31;
    ((unsigned*)&xnS[c][0])[dw] = xsrc[(((size_t)(b * CC + c)) * LL + l0) / 2 + dw];
  }
#pragma unroll
  for (int k = 0; k < 32; k++) {           // y2 tile: coalesced per g-chunk
    int idx = tid + k * 256;
    int g = idx >> 11, rem = idx & 2047;
    const unsigned* ysrc = (const unsigned*)(y2ws + (((size_t)(g * BB + b)) * LL + l0) * DI);
    y2S[g][(rem >> 5) * 33 + (rem & 31)] = ysrc[rem];
  }
  __syncthreads();
  int j = tid & 63, g = tid >> 6;
  float xcol[32];
#pragma unroll
  for (int r = 0; r < 32; r++)
    xcol[r] = us2f(xnS[g * 32 + r][j]);
  float acc[DI];
#pragma unroll
  for (int d = 0; d < DI; d++) {           // z projection — unrolled: acc stays in VGPRs
    const float* w = in_proj_w + (DI + d) * DM;
    float a = 0.f;
#pragma unroll
    for (int r = 0; r < 32; r++) a = fmaf(xcol[r], w[r], a);
    acc[d] = a;
  }
  const unsigned* yrow = &y2S[g][j * 33];
#pragma unroll
  for (int k = 0; k < 32; k++) {           // gate: y3 = y2 * silu(z)
    unsigned v = yrow[k];
    float z0 = acc[2 * k], z1 = acc[2 * k + 1];
    acc[2 * k]     = blo(v) * (z0 * sigmoidf_(z0));
    acc[2 * k + 1] = bhi(v) * (z1 * sigmoidf_(z1));
  }
  float* ob = out + ((size_t)(b * CC + g * DM)) * LL + l0 + j;
  for (int jj = 0; jj < DM; jj++) {        // out_proj + residual (inner unrolled: const acc idx)
    const float* w = out_proj_w + jj * DI;
    float a = us2f(xnS[g * 32 + jj][j]);   // residual xn
#pragma unroll
    for (int d = 0; d < DI; d++) a = fmaf(acc[d], w[d], a);
    ob[(size_t)jj * LL] = a;               // coalesced 256B
  }
}

extern "C" void kernel_launch(void* const* d_in, const int* in_sizes, int n_in,
                              void* d_out, int out_size, void* d_ws, size_t ws_size,
                              hipStream_t stream) {
  const float* input     = (const float*)d_in[0];
  const float* ln_g      = (const float*)d_in[1];
  const float* ln_b      = (const float*)d_in[2];
  const float* in_proj_w = (const float*)d_in[3];
  const float* conv_w    = (const float*)d_in[4];
  const float* conv_b    = (const float*)d_in[5];
  const float* x_proj_w  = (const float*)d_in[6];
  const float* dt_proj_w = (const float*)d_in[7];
  const float* dt_proj_b = (const float*)d_in[8];
  const float* A_log     = (const float*)d_in[9];
  const float* Dw        = (const float*)d_in[10];
  const float* out_proj_w= (const float*)d_in[11];
  float* out = (float*)d_out;

  char* ws = (char*)d_ws;
  bf*    u_ws     = (bf*)(ws);                    // 32 MiB
  bf*    delta_ws = (bf*)(ws + 33554432);         // 32 MiB (y2 aliases after k5)
  bf*    Bws      = (bf*)(ws + 67108864);         // 8 MiB
  bf*    Cws      = (bf*)(ws + 75497472);         // 8 MiB
  bf*    xn_ws    = (bf*)(ws + 83886080);         // 16 MiB
  float* hloc     = (float*)(ws + 100663296);     // 16 MiB (hin aliases)
  float* Aprod    = (float*)(ws + 117440512);     // 16 MiB  -> total 128 MiB
  (void)in_sizes; (void)n_in; (void)out_size; (void)ws_size;

  hipLaunchKernelGGL(k1_ln_conv, dim3(BB * NT), dim3(256), 0, stream,
                     input, ln_g, ln_b, in_proj_w, conv_w, conv_b, u_ws, xn_ws);
  hipLaunchKernelGGL(k2_xproj, dim3(1024), dim3(256), 0, stream,
                     u_ws, x_proj_w, dt_proj_w, dt_proj_b, delta_ws, Bws, Cws);
  hipLaunchKernelGGL(k3_scanA, dim3(GG * NC), dim3(64), 0, stream,
                     delta_ws, u_ws, Bws, A_log, hloc, Aprod);
  hipLaunchKernelGGL(k4_combine, dim3(GG), dim3(64), 0, stream,
                     Aprod, hloc);
  hipLaunchKernelGGL(k5_scanC, dim3(GG * NC), dim3(64), 0, stream,
                     delta_ws, u_ws, Bws, Cws, A_log, Dw, hloc);
  hipLaunchKernelGGL(k6_final, dim3(1024), dim3(256), 0, stream,
                     xn_ws, in_proj_w, out_proj_w, delta_ws, out);
}

// Round 7
// 414.466 us; speedup vs baseline: 1.5160x; 1.1781x over previous
//
#include <hip/hip_runtime.h>
#include <hip/hip_bf16.h>
#include <math.h>

typedef __hip_bfloat16 bf;

#define BB   16     // batch
#define CC   128    // channels
#define LL   4096   // H*W
#define DM   32     // d_model per chunk
#define DI   64     // d_inner
#define DSN  16     // d_state
#define GG   64     // 4 * BB sequences
#define NC   64     // scan chunks
#define CL   64     // LL / NC
#define TLV  61     // valid output columns per k1 tile (64 loaded, 3 head)
#define NT   68     // ceil(LL / TLV)
#define XS   133    // k1 xnT row stride in dwords (odd -> conflict-free)
#define YS   35     // k1 xiS row stride in dwords
#define XROW 20     // xdbl row stride in dwords (80 B: dw0=dt01, dw1-3 pad, dw4-11=B, dw12-19=C)

__device__ __forceinline__ float bf2f(bf x) { return __bfloat162float(x); }
__device__ __forceinline__ bf f2bf(float x) { return __float2bfloat16(x); }
__device__ __forceinline__ float blo(unsigned v) { return __uint_as_float(v << 16); }
__device__ __forceinline__ float bhi(unsigned v) { return __uint_as_float(v & 0xffff0000u); }
__device__ __forceinline__ float us2f(unsigned short v) { return __uint_as_float((unsigned)v << 16); }
__device__ __forceinline__ unsigned pack2(float a, float b) {
  bf ba = f2bf(a), bb = f2bf(b);
  unsigned short ua = *(unsigned short*)&ba, ub = *(unsigned short*)&bb;
  return (unsigned)ua | ((unsigned)ub << 16);
}

#if __has_builtin(__builtin_amdgcn_exp2f)
#define EXP2F(x) __builtin_amdgcn_exp2f(x)
#else
#define EXP2F(x) exp2f(x)
#endif

__device__ __forceinline__ float sigmoidf_(float x) { return 1.0f / (1.0f + __expf(-x)); }
// fast softplus: max(x,0) + ln2 * log2(1 + exp2(-|x|*log2e))  (v_exp_f32 + v_log_f32)
__device__ __forceinline__ float softplus_fast(float x) {
  float t = EXP2F(-fabsf(x) * 1.44269504088896f);
  return fmaxf(x, 0.0f) + 0.69314718056f * __log2f(1.0f + t);
}
__device__ __forceinline__ void unpack8(uint4 v, float* o) {
  o[0] = blo(v.x); o[1] = bhi(v.x); o[2] = blo(v.y); o[3] = bhi(v.y);
  o[4] = blo(v.z); o[5] = bhi(v.z); o[6] = blo(v.w); o[7] = bhi(v.w);
}

// A2[n] == (n+1)*A2[0] for this problem's A = arange(1..16); guarded fast path.
__device__ __forceinline__ bool ladder_ok(const float* A2) {
  bool ok = true;
#pragma unroll
  for (int n = 0; n < DSN; n++) {
    float r = A2[n] / A2[0];
    ok = ok && (fabsf(r - (float)(n + 1)) < 1e-3f);
  }
  return ok;
}

// ---------------- K1: layernorm + in_proj(xi) + causal conv + silu -> u (bf16), xn (bf16) ----------------
// (unchanged from round 6)
__global__ __launch_bounds__(256, 4) void k1_ln_conv(
    const float* __restrict__ input, const float* __restrict__ ln_g, const float* __restrict__ ln_b,
    const float* __restrict__ in_proj_w, const float* __restrict__ conv_w, const float* __restrict__ conv_b,
    bf* __restrict__ u_ws, bf* __restrict__ xn_ws) {
  __shared__ unsigned ldsbuf[8960];               // union: xnT fp32 64x133dw / xiS bf16 256x35dw
  __shared__ float mu_s[64], rs_s[64];
  float* xnT = (float*)ldsbuf;
  unsigned short* xiS = (unsigned short*)ldsbuf;
  int b = blockIdx.x / NT;
  int tile = blockIdx.x - b * NT;
  int l0 = tile * TLV;
  int tid = threadIdx.x;
  const float* inb = input + (size_t)b * CC * LL;
#pragma unroll
  for (int k = 0; k < 32; k++) {
    int i = tid + k * 256;
    int j = i & 63, c = i >> 6;
    int l = l0 - 3 + j;
    xnT[j * XS + c] = (l >= 0 && l < LL) ? inb[c * LL + l] : 0.0f;
  }
  __syncthreads();
  if (tid < 64) {
    float s = 0.f, s2 = 0.f;
    for (int c = 0; c < CC; c++) { float v = xnT[tid * XS + c]; s += v; s2 = fmaf(v, v, s2); }
    float mu = s * (1.0f / CC);
    float var = s2 * (1.0f / CC) - mu * mu;
    mu_s[tid] = mu;
    rs_s[tid] = rsqrtf(var + 1e-5f);
  }
  __syncthreads();
#pragma unroll
  for (int k = 0; k < 32; k++) {
    int i = tid + k * 256;
    int j = i & 63, c = i >> 6;
    xnT[j * XS + c] = (xnT[j * XS + c] - mu_s[j]) * rs_s[j] * ln_g[c] + ln_b[c];
  }
  __syncthreads();
  for (int i = tid; i < CC * TLV; i += 256) {
    int c = i / TLV, j2 = i - c * TLV;
    int l = l0 + j2;
    if (l < LL) xn_ws[((size_t)(b * CC + c)) * LL + l] = f2bf(xnT[(j2 + 3) * XS + c]);
  }
  int g = tid >> 6, j = tid & 63;
  float xr[32];
#pragma unroll
  for (int r = 0; r < 32; r++) xr[r] = xnT[j * XS + g * DM + r];
  bool zero_col = (l0 - 3 + j < 0);
  __syncthreads();
#pragma unroll
  for (int c2 = 0; c2 < 4; c2++) {
    float acc[16];
#pragma unroll
    for (int dd = 0; dd < 16; dd++) {
      const float* w = in_proj_w + (c2 * 16 + dd) * DM;
      float a = 0.f;
#pragma unroll
      for (int r = 0; r < 32; r++) a = fmaf(xr[r], w[r], a);
      acc[dd] = zero_col ? 0.f : a;
    }
    unsigned* xo = (unsigned*)&ldsbuf[(g * 64 + j) * YS + c2 * 8];
#pragma unroll
    for (int k = 0; k < 8; k++)
      xo[k] = pack2(acc[2 * k], acc[2 * k + 1]);
  }
  __syncthreads();
  int d = j;
  float cw0 = conv_w[d * 4 + 0], cw1 = conv_w[d * 4 + 1];
  float cw2 = conv_w[d * 4 + 2], cw3 = conv_w[d * 4 + 3];
  float cb = conv_b[d];
  bf* uo = u_ws + (size_t)(g * BB + b) * LL * DI + d;
  float x3 = 0.f, x2 = 0.f, x1 = 0.f, x0 = 0.f;
  for (int jj = 0; jj < 64; jj++) {
    float xi = us2f(xiS[(g * 64 + jj) * (2 * YS) + d]);
    x3 = x2; x2 = x1; x1 = x0; x0 = xi;
    int l = l0 + jj - 3;
    if (jj >= 3 && l < LL) {
      float pre = x3 * cw0 + x2 * cw1 + x1 * cw2 + x0 * cw3 + cb;
      float uu = pre * sigmoidf_(pre);
      uo[(size_t)l * DI] = f2bf(uu);
    }
  }
}

// ---------------- K2: x_proj only -> xdbl rows (dt0,dt1,B,C packed bf16, 80 B/pos) ----------------
// grid: 1024 blocks, 256 threads; one position per thread; LDS = uS only (33.8 KB -> 4 blocks/CU).
__global__ __launch_bounds__(256) void k2_xproj(
    const bf* __restrict__ u_ws, const float* __restrict__ x_proj_w,
    unsigned* __restrict__ xdbl) {
  __shared__ unsigned uS[256 * 33];      // 256 rows x 32 dwords, stride 33 -> conflict-free
  int tid = threadIdx.x;
  size_t pos0 = (size_t)blockIdx.x * 256;
  const unsigned* src = (const unsigned*)u_ws + pos0 * 32;
#pragma unroll
  for (int k = 0; k < 32; k++) {         // coalesced fill
    int idx = tid + k * 256;
    uS[(idx >> 5) * 33 + (idx & 31)] = src[idx];
  }
  __syncthreads();
  float xdb[34];
#pragma unroll
  for (int e = 0; e < 34; e++) xdb[e] = 0.f;
#pragma unroll
  for (int c2 = 0; c2 < 4; c2++) {       // register-blocked: 16 u-values live at a time
    float f[16];
#pragma unroll
    for (int k = 0; k < 8; k++) {
      unsigned v = uS[tid * 33 + c2 * 8 + k];
      f[2 * k] = blo(v); f[2 * k + 1] = bhi(v);
    }
#pragma unroll
    for (int e = 0; e < 34; e++) {       // weights wave-uniform -> s_load
      const float* w = x_proj_w + e * DI + c2 * 16;
      float a = xdb[e];
#pragma unroll
      for (int i = 0; i < 16; i++) a = fmaf(f[i], w[i], a);
      xdb[e] = a;
    }
  }
  // pack into own row (thread-owned: all own-row reads already done; no barrier needed)
  unsigned* row = &uS[tid * 33];
  row[0] = pack2(xdb[0], xdb[1]);        // dt pair; dw1-3 left as stale u (pad, never read)
#pragma unroll
  for (int n = 0; n < 8; n++) row[4 + n]  = pack2(xdb[2 + 2 * n], xdb[3 + 2 * n]);   // B
#pragma unroll
  for (int n = 0; n < 8; n++) row[12 + n] = pack2(xdb[18 + 2 * n], xdb[19 + 2 * n]); // C
  __syncthreads();
  unsigned* dst = xdbl + pos0 * XROW;
#pragma unroll
  for (int k = 0; k < XROW; k++) {       // coalesced flush of 20-dw rows
    int idx = tid + k * 256;
    int r = idx / XROW, c = idx - r * XROW;
    dst[idx] = uS[r * 33 + c];
  }
}

// ---------------- K3: scan pass A — local states + chunk delta-sums (delta computed inline) ----------------
// grid: GG*NC = 4096 blocks, 64 threads (1 wave, lane = d).
__global__ __launch_bounds__(64) void k3_scanA(
    const unsigned* __restrict__ xdbl, const bf* __restrict__ u_ws,
    const float* __restrict__ A_log, const float* __restrict__ dt_proj_w,
    const float* __restrict__ dt_proj_b,
    float* __restrict__ hloc, float* __restrict__ ssum_ws) {
  int s = blockIdx.x >> 6, chunk = blockIdx.x & (NC - 1);
  int d = threadIdx.x;
  float A2[DSN];
#pragma unroll
  for (int n = 0; n < DSN; n++)
    A2[n] = -__expf(A_log[d * DSN + n]) * 1.44269504088896f;  // A * log2(e)
  bool ok = ladder_ok(A2);
  float w0 = dt_proj_w[2 * d], w1 = dt_proj_w[2 * d + 1], bd = dt_proj_b[d];
  float h[DSN];
#pragma unroll
  for (int n = 0; n < DSN; n++) h[n] = 0.f;
  float ss = 0.f;
  size_t base = (size_t)s * LL + (size_t)chunk * CL;
  const unsigned short* up = (const unsigned short*)u_ws + base * DI + d;
  const unsigned* xrow = xdbl + base * XROW;
  if (ok) {
    float a0 = A2[0];
    for (int t = 0; t < CL; t++) {
      const unsigned* r = xrow + t * XROW;         // wave-uniform -> scalar loads
      unsigned dtp = r[0];
      float x = fmaf(bhi(dtp), w1, fmaf(blo(dtp), w0, bd));
      float delta = softplus_fast(x);
      float uu = us2f(up[(size_t)t * DI]);
      float Bv[16];
      unpack8(((const uint4*)(r + 4))[0], Bv);
      unpack8(((const uint4*)(r + 4))[1], Bv + 8);
      float du = delta * uu;
      ss += delta;
      float E = EXP2F(delta * a0);
      float e = E;
#pragma unroll
      for (int n = 0; n < DSN; n++) {
        h[n] = fmaf(h[n], e, du * Bv[n]);
        e *= E;
      }
    }
  } else {
    for (int t = 0; t < CL; t++) {
      const unsigned* r = xrow + t * XROW;
      unsigned dtp = r[0];
      float x = fmaf(bhi(dtp), w1, fmaf(blo(dtp), w0, bd));
      float delta = softplus_fast(x);
      float uu = us2f(up[(size_t)t * DI]);
      float Bv[16];
      unpack8(((const uint4*)(r + 4))[0], Bv);
      unpack8(((const uint4*)(r + 4))[1], Bv + 8);
      float du = delta * uu;
      ss += delta;
#pragma unroll
      for (int n = 0; n < DSN; n++) {
        float e = EXP2F(delta * A2[n]);
        h[n] = fmaf(h[n], e, du * Bv[n]);
      }
    }
  }
  size_t ob = (size_t)blockIdx.x * (DSN * DI) + d;
#pragma unroll
  for (int n = 0; n < DSN; n++) hloc[ob + n * DI] = h[n];
  ssum_ws[blockIdx.x * DI + d] = ss;
}

// ---------------- K4: cross-chunk combine; Aprod recomputed from ssum; hin overwrites hloc ----------------
// grid: GG blocks, 64 threads.
__global__ __launch_bounds__(64) void k4_combine(
    const float* __restrict__ ssum_ws, const float* __restrict__ A_log, float* hloc_hin) {
  int s = blockIdx.x, d = threadIdx.x;
  float A2[DSN];
#pragma unroll
  for (int n = 0; n < DSN; n++)
    A2[n] = -__expf(A_log[d * DSN + n]) * 1.44269504088896f;
  float h[DSN];
#pragma unroll
  for (int n = 0; n < DSN; n++) h[n] = 0.f;
  for (int k = 0; k < NC; k++) {
    size_t base = (size_t)(s * NC + k) * (DSN * DI) + d;
    float ss = ssum_ws[(s * NC + k) * DI + d];
#pragma unroll
    for (int n = 0; n < DSN; n++) {
      float ap = EXP2F(A2[n] * ss);
      float hl = hloc_hin[base + n * DI];
      hloc_hin[base + n * DI] = h[n];              // write h_in over h_loc
      h[n] = fmaf(h[n], ap, hl);
    }
  }
}

// ---------------- K56: scan pass C (y2 -> LDS) + z-gate + out_proj + residual -> output (fp32) ----------------
// grid: BB*NC = 1024 blocks (b, chunk), 256 threads. Wave g scans sequence s=g*BB+b over the chunk;
// xn tile prefetched to registers before the scan (loads complete under the scan); after barrier,
// thread=(g,j) does gate + out_proj from LDS. y2 never touches HBM.
__global__ __launch_bounds__(256, 3) void k56_scan_final(
    const unsigned* __restrict__ xdbl, const bf* __restrict__ u_ws,
    const float* __restrict__ A_log, const float* __restrict__ dt_proj_w,
    const float* __restrict__ dt_proj_b, const float* __restrict__ Dw,
    const float* __restrict__ hin, const bf* __restrict__ xn_ws,
    const float* __restrict__ in_proj_w, const float* __restrict__ out_proj_w,
    float* __restrict__ out) {
  __shared__ unsigned y2S[4 * 64 * 33];            // per-g: 64 rows(t) x 33 dw (d-pairs), 33.8 KB
  __shared__ unsigned short xnS[CC][66];           // row stride 33 dw, 16.9 KB
  int b = blockIdx.x >> 6;
  int chunk = blockIdx.x & (NC - 1);
  int l0 = chunk * CL;
  int tid = threadIdx.x;
  int g = tid >> 6, d = tid & 63;
  // prefetch xn tile into regs (coalesced); ds_write deferred until after the scan
  unsigned xnreg[16];
  const unsigned* xsrc = (const unsigned*)xn_ws;
#pragma unroll
  for (int k = 0; k < 16; k++) {
    int idx = tid + k * 256;
    int c = idx >> 5, dw = idx & 31;
    xnreg[k] = xsrc[(((size_t)(b * CC + c)) * LL + l0) / 2 + dw];
  }
  // ---- scan (wave = g, lane = d) ----
  int s = g * BB + b;
  float A2[DSN];
#pragma unroll
  for (int n = 0; n < DSN; n++)
    A2[n] = -__expf(A_log[d * DSN + n]) * 1.44269504088896f;
  bool ok = ladder_ok(A2);
  float w0 = dt_proj_w[2 * d], w1 = dt_proj_w[2 * d + 1], bd = dt_proj_b[d];
  float Dd = Dw[d];
  float h[DSN];
  size_t hb = (size_t)(s * NC + chunk) * (DSN * DI) + d;
#pragma unroll
  for (int n = 0; n < DSN; n++) h[n] = hin[hb + n * DI];
  size_t base = (size_t)s * LL + (size_t)chunk * CL;
  const unsigned short* up = (const unsigned short*)u_ws + base * DI + d;
  const unsigned* xrow = xdbl + base * XROW;
  unsigned short* yout = (unsigned short*)y2S + g * 4224 + d;   // + t*66 per step
  if (ok) {
    float a0 = A2[0];
    for (int t = 0; t < CL; t++) {
      const unsigned* r = xrow + t * XROW;
      unsigned dtp = r[0];
      float x = fmaf(bhi(dtp), w1, fmaf(blo(dtp), w0, bd));
      float delta = softplus_fast(x);
      float uu = us2f(up[(size_t)t * DI]);
      float Bv[16], Cv[16];
      unpack8(((const uint4*)(r + 4))[0], Bv);
      unpack8(((const uint4*)(r + 4))[1], Bv + 8);
      unpack8(((const uint4*)(r + 12))[0], Cv);
      unpack8(((const uint4*)(r + 12))[1], Cv + 8);
      float du = delta * uu;
      float y = 0.f;
      float E = EXP2F(delta * a0);
      float e = E;
#pragma unroll
      for (int n = 0; n < DSN; n++) {
        h[n] = fmaf(h[n], e, du * Bv[n]);
        y = fmaf(h[n], Cv[n], y);
        e *= E;
      }
      bf rv = f2bf(y + uu * Dd);
      yout[t * 66] = *(unsigned short*)&rv;        // 2 B/lane contiguous: 2-way bank (free)
    }
  } else {
    for (int t = 0; t < CL; t++) {
      const unsigned* r = xrow + t * XROW;
      unsigned dtp = r[0];
      float x = fmaf(bhi(dtp), w1, fmaf(blo(dtp), w0, bd));
      float delta = softplus_fast(x);
      float uu = us2f(up[(size_t)t * DI]);
      float Bv[16], Cv[16];
      unpack8(((const uint4*)(r + 4))[0], Bv);
      unpack8(((const uint4*)(r + 4))[1], Bv + 8);
      unpack8(((const uint4*)(r + 12))[0], Cv);
      unpack8(((const uint4*)(r + 12))[1], Cv + 8);
      float du = delta * uu;
      float y = 0.f;
#pragma unroll
      for (int n = 0; n < DSN; n++) {
        float e = EXP2F(delta * A2[n]);
        h[n] = fmaf(h[n], e, du * Bv[n]);
        y = fmaf(h[n], Cv[n], y);
      }
      bf rv = f2bf(y + uu * Dd);
      yout[t * 66] = *(unsigned short*)&rv;
    }
  }
  // stage xn tile to LDS
#pragma unroll
  for (int k = 0; k < 16; k++) {
    int idx = tid + k * 256;
    int c = idx >> 5, dw = idx & 31;
    ((unsigned*)&xnS[c][0])[dw] = xnreg[k];
  }
  __syncthreads();
  // ---- gate + out_proj + residual (thread = (g, column j)) ----
  int j = d;
  float xcol[32];
#pragma unroll
  for (int rr = 0; rr < 32; rr++)
    xcol[rr] = us2f(xnS[g * 32 + rr][j]);
  float acc[DI];
#pragma unroll
  for (int dd = 0; dd < DI; dd++) {                // z projection; weights wave-uniform -> s_load
    const float* w = in_proj_w + (DI + dd) * DM;
    float a = 0.f;
#pragma unroll
    for (int rr = 0; rr < 32; rr++) a = fmaf(xcol[rr], w[rr], a);
    acc[dd] = a;
  }
  const unsigned* yrow = y2S + g * 2112 + j * 33;  // banks (j+k)%32 -> conflict-free
#pragma unroll
  for (int k = 0; k < 32; k++) {                   // gate: y3 = y2 * silu(z)
    unsigned v = yrow[k];
    float z0 = acc[2 * k], z1 = acc[2 * k + 1];
    acc[2 * k]     = blo(v) * (z0 * sigmoidf_(z0));
    acc[2 * k + 1] = bhi(v) * (z1 * sigmoidf_(z1));
  }
  float* ob = out + ((size_t)(b * CC + g * DM)) * LL + l0 + j;
  for (int jj = 0; jj < DM; jj++) {                // out_proj + residual
    const float* w = out_proj_w + jj * DI;
    float a = us2f(xnS[g * 32 + jj][j]);           // residual xn
#pragma unroll
    for (int dd = 0; dd < DI; dd++) a = fmaf(acc[dd], w[dd], a);
    ob[(size_t)jj * LL] = a;                       // coalesced 256B
  }
}

extern "C" void kernel_launch(void* const* d_in, const int* in_sizes, int n_in,
                              void* d_out, int out_size, void* d_ws, size_t ws_size,
                              hipStream_t stream) {
  const float* input     = (const float*)d_in[0];
  const float* ln_g      = (const float*)d_in[1];
  const float* ln_b      = (const float*)d_in[2];
  const float* in_proj_w = (const float*)d_in[3];
  const float* conv_w    = (const float*)d_in[4];
  const float* conv_b    = (const float*)d_in[5];
  const float* x_proj_w  = (const float*)d_in[6];
  const float* dt_proj_w = (const float*)d_in[7];
  const float* dt_proj_b = (const float*)d_in[8];
  const float* A_log     = (const float*)d_in[9];
  const float* Dw        = (const float*)d_in[10];
  const float* out_proj_w= (const float*)d_in[11];
  float* out = (float*)d_out;

  char* ws = (char*)d_ws;
  bf*       u_ws  = (bf*)(ws);                    // 32 MiB
  unsigned* xdbl  = (unsigned*)(ws + 33554432);   // 262144 * 80 B = 20 MiB
  bf*       xn_ws = (bf*)(ws + 54525952);         // 16 MiB
  float*    hloc  = (float*)(ws + 71303168);      // 16 MiB (hin aliases after k4)
  float*    ssum  = (float*)(ws + 88080384);      // 1 MiB   -> total 85 MiB
  (void)in_sizes; (void)n_in; (void)out_size; (void)ws_size;

  hipLaunchKernelGGL(k1_ln_conv, dim3(BB * NT), dim3(256), 0, stream,
                     input, ln_g, ln_b, in_proj_w, conv_w, conv_b, u_ws, xn_ws);
  hipLaunchKernelGGL(k2_xproj, dim3(1024), dim3(256), 0, stream,
                     u_ws, x_proj_w, xdbl);
  hipLaunchKernelGGL(k3_scanA, dim3(GG * NC), dim3(64), 0, stream,
                     xdbl, u_ws, A_log, dt_proj_w, dt_proj_b, hloc, ssum);
  hipLaunchKernelGGL(k4_combine, dim3(GG), dim3(64), 0, stream,
                     ssum, A_log, hloc);
  hipLaunchKernelGGL(k56_scan_final, dim3(BB * NC), dim3(256), 0, stream,
                     xdbl, u_ws, A_log, dt_proj_w, dt_proj_b, Dw, hloc, xn_ws,
                     in_proj_w, out_proj_w, out);
}

// Round 8
// 397.238 us; speedup vs baseline: 1.5818x; 1.0434x over previous
//
#include <hip/hip_runtime.h>
#include <hip/hip_bf16.h>
#include <math.h>

typedef __hip_bfloat16 bf;

#define BB   16     // batch
#define CC   128    // channels
#define LL   4096   // H*W
#define DM   32     // d_model per chunk
#define DI   64     // d_inner
#define DSN  16     // d_state
#define GG   64     // 4 * BB sequences
#define NC   64     // scan chunks
#define CL   64     // LL / NC
#define TLV  61     // valid output columns per k1 tile (64 loaded, 3 head)
#define NT   68     // ceil(LL / TLV)
#define XS   133    // k1 xnT row stride in dwords (odd -> conflict-free)
#define YS   35     // k1 xiS row stride in dwords
#define XROW 20     // xdbl row stride in dwords (80 B: dw0=dt01, dw1-3 pad, dw4-11=B, dw12-19=C)

__device__ __forceinline__ float bf2f(bf x) { return __bfloat162float(x); }
__device__ __forceinline__ bf f2bf(float x) { return __float2bfloat16(x); }
__device__ __forceinline__ float blo(unsigned v) { return __uint_as_float(v << 16); }
__device__ __forceinline__ float bhi(unsigned v) { return __uint_as_float(v & 0xffff0000u); }
__device__ __forceinline__ float us2f(unsigned short v) { return __uint_as_float((unsigned)v << 16); }
__device__ __forceinline__ unsigned pack2(float a, float b) {
  bf ba = f2bf(a), bb = f2bf(b);
  unsigned short ua = *(unsigned short*)&ba, ub = *(unsigned short*)&bb;
  return (unsigned)ua | ((unsigned)ub << 16);
}

#if __has_builtin(__builtin_amdgcn_exp2f)
#define EXP2F(x) __builtin_amdgcn_exp2f(x)
#else
#define EXP2F(x) exp2f(x)
#endif

__device__ __forceinline__ float sigmoidf_(float x) { return 1.0f / (1.0f + __expf(-x)); }
// fast softplus: max(x,0) + ln2 * log2(1 + exp2(-|x|*log2e))
__device__ __forceinline__ float softplus_fast(float x) {
  float t = EXP2F(-fabsf(x) * 1.44269504088896f);
  return fmaxf(x, 0.0f) + 0.69314718056f * __log2f(1.0f + t);
}
__device__ __forceinline__ void unpack8(uint4 v, float* o) {
  o[0] = blo(v.x); o[1] = bhi(v.x); o[2] = blo(v.y); o[3] = bhi(v.y);
  o[4] = blo(v.z); o[5] = bhi(v.z); o[6] = blo(v.w); o[7] = bhi(v.w);
}

// ---------------- K1: layernorm + in_proj(xi) + causal conv + silu -> u (bf16), xn (bf16) ----------------
// (unchanged from round 7)
__global__ __launch_bounds__(256, 4) void k1_ln_conv(
    const float* __restrict__ input, const float* __restrict__ ln_g, const float* __restrict__ ln_b,
    const float* __restrict__ in_proj_w, const float* __restrict__ conv_w, const float* __restrict__ conv_b,
    bf* __restrict__ u_ws, bf* __restrict__ xn_ws) {
  __shared__ unsigned ldsbuf[8960];               // union: xnT fp32 64x133dw / xiS bf16 256x35dw
  __shared__ float mu_s[64], rs_s[64];
  float* xnT = (float*)ldsbuf;
  unsigned short* xiS = (unsigned short*)ldsbuf;
  int b = blockIdx.x / NT;
  int tile = blockIdx.x - b * NT;
  int l0 = tile * TLV;
  int tid = threadIdx.x;
  const float* inb = input + (size_t)b * CC * LL;
#pragma unroll
  for (int k = 0; k < 32; k++) {
    int i = tid + k * 256;
    int j = i & 63, c = i >> 6;
    int l = l0 - 3 + j;
    xnT[j * XS + c] = (l >= 0 && l < LL) ? inb[c * LL + l] : 0.0f;
  }
  __syncthreads();
  if (tid < 64) {
    float s = 0.f, s2 = 0.f;
    for (int c = 0; c < CC; c++) { float v = xnT[tid * XS + c]; s += v; s2 = fmaf(v, v, s2); }
    float mu = s * (1.0f / CC);
    float var = s2 * (1.0f / CC) - mu * mu;
    mu_s[tid] = mu;
    rs_s[tid] = rsqrtf(var + 1e-5f);
  }
  __syncthreads();
#pragma unroll
  for (int k = 0; k < 32; k++) {
    int i = tid + k * 256;
    int j = i & 63, c = i >> 6;
    xnT[j * XS + c] = (xnT[j * XS + c] - mu_s[j]) * rs_s[j] * ln_g[c] + ln_b[c];
  }
  __syncthreads();
  for (int i = tid; i < CC * TLV; i += 256) {
    int c = i / TLV, j2 = i - c * TLV;
    int l = l0 + j2;
    if (l < LL) xn_ws[((size_t)(b * CC + c)) * LL + l] = f2bf(xnT[(j2 + 3) * XS + c]);
  }
  int g = tid >> 6, j = tid & 63;
  float xr[32];
#pragma unroll
  for (int r = 0; r < 32; r++) xr[r] = xnT[j * XS + g * DM + r];
  bool zero_col = (l0 - 3 + j < 0);
  __syncthreads();
#pragma unroll
  for (int c2 = 0; c2 < 4; c2++) {
    float acc[16];
#pragma unroll
    for (int dd = 0; dd < 16; dd++) {
      const float* w = in_proj_w + (c2 * 16 + dd) * DM;
      float a = 0.f;
#pragma unroll
      for (int r = 0; r < 32; r++) a = fmaf(xr[r], w[r], a);
      acc[dd] = zero_col ? 0.f : a;
    }
    unsigned* xo = (unsigned*)&ldsbuf[(g * 64 + j) * YS + c2 * 8];
#pragma unroll
    for (int k = 0; k < 8; k++)
      xo[k] = pack2(acc[2 * k], acc[2 * k + 1]);
  }
  __syncthreads();
  int d = j;
  float cw0 = conv_w[d * 4 + 0], cw1 = conv_w[d * 4 + 1];
  float cw2 = conv_w[d * 4 + 2], cw3 = conv_w[d * 4 + 3];
  float cb = conv_b[d];
  bf* uo = u_ws + (size_t)(g * BB + b) * LL * DI + d;
  float x3 = 0.f, x2 = 0.f, x1 = 0.f, x0 = 0.f;
  for (int jj = 0; jj < 64; jj++) {
    float xi = us2f(xiS[(g * 64 + jj) * (2 * YS) + d]);
    x3 = x2; x2 = x1; x1 = x0; x0 = xi;
    int l = l0 + jj - 3;
    if (jj >= 3 && l < LL) {
      float pre = x3 * cw0 + x2 * cw1 + x1 * cw2 + x0 * cw3 + cb;
      float uu = pre * sigmoidf_(pre);
      uo[(size_t)l * DI] = f2bf(uu);
    }
  }
}

// ---------------- K2: x_proj only -> xdbl rows (dt0,dt1,B,C packed bf16, 80 B/pos) ----------------
// (unchanged from round 7)
__global__ __launch_bounds__(256) void k2_xproj(
    const bf* __restrict__ u_ws, const float* __restrict__ x_proj_w,
    unsigned* __restrict__ xdbl) {
  __shared__ unsigned uS[256 * 33];
  int tid = threadIdx.x;
  size_t pos0 = (size_t)blockIdx.x * 256;
  const unsigned* src = (const unsigned*)u_ws + pos0 * 32;
#pragma unroll
  for (int k = 0; k < 32; k++) {
    int idx = tid + k * 256;
    uS[(idx >> 5) * 33 + (idx & 31)] = src[idx];
  }
  __syncthreads();
  float xdb[34];
#pragma unroll
  for (int e = 0; e < 34; e++) xdb[e] = 0.f;
#pragma unroll
  for (int c2 = 0; c2 < 4; c2++) {
    float f[16];
#pragma unroll
    for (int k = 0; k < 8; k++) {
      unsigned v = uS[tid * 33 + c2 * 8 + k];
      f[2 * k] = blo(v); f[2 * k + 1] = bhi(v);
    }
#pragma unroll
    for (int e = 0; e < 34; e++) {
      const float* w = x_proj_w + e * DI + c2 * 16;
      float a = xdb[e];
#pragma unroll
      for (int i = 0; i < 16; i++) a = fmaf(f[i], w[i], a);
      xdb[e] = a;
    }
  }
  unsigned* row = &uS[tid * 33];
  row[0] = pack2(xdb[0], xdb[1]);
#pragma unroll
  for (int n = 0; n < 8; n++) row[4 + n]  = pack2(xdb[2 + 2 * n], xdb[3 + 2 * n]);
#pragma unroll
  for (int n = 0; n < 8; n++) row[12 + n] = pack2(xdb[18 + 2 * n], xdb[19 + 2 * n]);
  __syncthreads();
  unsigned* dst = xdbl + pos0 * XROW;
#pragma unroll
  for (int k = 0; k < XROW; k++) {
    int idx = tid + k * 256;
    int r = idx / XROW, c = idx - r * XROW;
    dst[idx] = uS[r * 33 + c];
  }
}

// A2[n] == (n+1)*A2[0] for this problem's A = arange(1..16); guarded fast path.
__device__ __forceinline__ bool ladder_check(const float* A_log, int d, float a0) {
  bool ok = true;
#pragma unroll
  for (int n = 1; n < DSN; n++) {
    float an = -__expf(A_log[d * DSN + n]) * 1.44269504088896f;
    ok = ok && (fabsf(an / a0 - (float)(n + 1)) < 1e-3f);
  }
  return ok;
}

// ---------------- K3: scan pass A — local states + chunk delta-sums ----------------
// (unchanged structure from round 7; blockIdx-derived address already scalar)
__global__ __launch_bounds__(64) void k3_scanA(
    const unsigned* __restrict__ xdbl, const bf* __restrict__ u_ws,
    const float* __restrict__ A_log, const float* __restrict__ dt_proj_w,
    const float* __restrict__ dt_proj_b,
    float* __restrict__ hloc, float* __restrict__ ssum_ws) {
  int s = blockIdx.x >> 6, chunk = blockIdx.x & (NC - 1);
  int d = threadIdx.x;
  float a0 = -__expf(A_log[d * DSN]) * 1.44269504088896f;
  bool ok = ladder_check(A_log, d, a0);
  float w0 = dt_proj_w[2 * d], w1 = dt_proj_w[2 * d + 1], bd = dt_proj_b[d];
  float h[DSN];
#pragma unroll
  for (int n = 0; n < DSN; n++) h[n] = 0.f;
  float ss = 0.f;
  size_t base = (size_t)s * LL + (size_t)chunk * CL;
  const unsigned short* up = (const unsigned short*)u_ws + base * DI + d;
  const unsigned* xrow = xdbl + base * XROW;
  if (ok) {
    for (int t = 0; t < CL; t++) {
      const unsigned* r = xrow + t * XROW;
      unsigned dtp = r[0];
      float x = fmaf(bhi(dtp), w1, fmaf(blo(dtp), w0, bd));
      float delta = softplus_fast(x);
      float uu = us2f(up[(size_t)t * DI]);
      float Bv[16];
      unpack8(((const uint4*)(r + 4))[0], Bv);
      unpack8(((const uint4*)(r + 4))[1], Bv + 8);
      float du = delta * uu;
      ss += delta;
      float E = EXP2F(delta * a0);
      float e = E;
#pragma unroll
      for (int n = 0; n < DSN; n++) {
        h[n] = fmaf(h[n], e, du * Bv[n]);
        e *= E;
      }
    }
  } else {
    float A2[DSN];
#pragma unroll
    for (int n = 0; n < DSN; n++)
      A2[n] = -__expf(A_log[d * DSN + n]) * 1.44269504088896f;
    for (int t = 0; t < CL; t++) {
      const unsigned* r = xrow + t * XROW;
      unsigned dtp = r[0];
      float x = fmaf(bhi(dtp), w1, fmaf(blo(dtp), w0, bd));
      float delta = softplus_fast(x);
      float uu = us2f(up[(size_t)t * DI]);
      float Bv[16];
      unpack8(((const uint4*)(r + 4))[0], Bv);
      unpack8(((const uint4*)(r + 4))[1], Bv + 8);
      float du = delta * uu;
      ss += delta;
#pragma unroll
      for (int n = 0; n < DSN; n++) {
        float e = EXP2F(delta * A2[n]);
        h[n] = fmaf(h[n], e, du * Bv[n]);
      }
    }
  }
  size_t ob = (size_t)blockIdx.x * (DSN * DI) + d;
#pragma unroll
  for (int n = 0; n < DSN; n++) hloc[ob + n * DI] = h[n];
  ssum_ws[blockIdx.x * DI + d] = ss;
}

// ---------------- K4: cross-chunk combine; Aprod recomputed from ssum; hin overwrites hloc ----------------
__global__ __launch_bounds__(64) void k4_combine(
    const float* __restrict__ ssum_ws, const float* __restrict__ A_log, float* hloc_hin) {
  int s = blockIdx.x, d = threadIdx.x;
  float A2[DSN];
#pragma unroll
  for (int n = 0; n < DSN; n++)
    A2[n] = -__expf(A_log[d * DSN + n]) * 1.44269504088896f;
  float h[DSN];
#pragma unroll
  for (int n = 0; n < DSN; n++) h[n] = 0.f;
  for (int k = 0; k < NC; k++) {
    size_t base = (size_t)(s * NC + k) * (DSN * DI) + d;
    float ss = ssum_ws[(s * NC + k) * DI + d];
#pragma unroll
    for (int n = 0; n < DSN; n++) {
      float ap = EXP2F(A2[n] * ss);
      float hl = hloc_hin[base + n * DI];
      hloc_hin[base + n * DI] = h[n];
      h[n] = fmaf(h[n], ap, hl);
    }
  }
}

// ---------------- K56: scan pass C (y2 -> LDS) + z-gate + out_proj + residual -> output (fp32) ----------------
// grid: BB*NC = 1024 blocks (b, chunk), 256 threads; LDS = y2S only (33792 B -> 4 blocks/CU).
// readfirstlane makes the sequence index an SGPR -> xdbl row loads become s_load (scalar),
// B/C ride as SGPR operands into the FMAs. Epilogue reads xn straight from global (coalesced).
__global__ __launch_bounds__(256, 4) void k56_scan_final(
    const unsigned* __restrict__ xdbl, const bf* __restrict__ u_ws,
    const float* __restrict__ A_log, const float* __restrict__ dt_proj_w,
    const float* __restrict__ dt_proj_b, const float* __restrict__ Dw,
    const float* __restrict__ hin, const bf* __restrict__ xn_ws,
    const float* __restrict__ in_proj_w, const float* __restrict__ out_proj_w,
    float* __restrict__ out) {
  __shared__ unsigned y2S[4 * 64 * 33];            // per-g: 64 rows(t) x 33 dw (d-pairs)
  int b = blockIdx.x >> 6;
  int chunk = blockIdx.x & (NC - 1);
  int l0 = chunk * CL;
  int tid = threadIdx.x;
  int g = tid >> 6, d = tid & 63;
  // wave-uniform sequence index, forced into an SGPR
  int s_u = __builtin_amdgcn_readfirstlane(g * BB + b);
  float a0 = -__expf(A_log[d * DSN]) * 1.44269504088896f;
  bool ok = ladder_check(A_log, d, a0);
  float w0 = dt_proj_w[2 * d], w1 = dt_proj_w[2 * d + 1], bd = dt_proj_b[d];
  float Dd = Dw[d];
  float h[DSN];
  size_t hb = (size_t)(s_u * NC + chunk) * (DSN * DI) + d;
#pragma unroll
  for (int n = 0; n < DSN; n++) h[n] = hin[hb + n * DI];
  size_t base = (size_t)s_u * LL + (size_t)chunk * CL;
  const unsigned short* up = (const unsigned short*)u_ws + base * DI + d;
  const unsigned* xrow = xdbl + base * XROW;       // scalar base -> s_load rows
  unsigned short* yout = (unsigned short*)y2S + g * 4224 + d;
  if (ok) {
    for (int t = 0; t < CL; t++) {
      const unsigned* r = xrow + t * XROW;
      unsigned dtp = r[0];
      float x = fmaf(bhi(dtp), w1, fmaf(blo(dtp), w0, bd));
      float delta = softplus_fast(x);
      float uu = us2f(up[(size_t)t * DI]);
      float Bv[16], Cv[16];
      unpack8(((const uint4*)(r + 4))[0], Bv);
      unpack8(((const uint4*)(r + 4))[1], Bv + 8);
      unpack8(((const uint4*)(r + 12))[0], Cv);
      unpack8(((const uint4*)(r + 12))[1], Cv + 8);
      float du = delta * uu;
      float y = 0.f;
      float E = EXP2F(delta * a0);
      float e = E;
#pragma unroll
      for (int n = 0; n < DSN; n++) {
        h[n] = fmaf(h[n], e, du * Bv[n]);
        y = fmaf(h[n], Cv[n], y);
        e *= E;
      }
      bf rv = f2bf(y + uu * Dd);
      yout[t * 66] = *(unsigned short*)&rv;
    }
  } else {
    float A2[DSN];
#pragma unroll
    for (int n = 0; n < DSN; n++)
      A2[n] = -__expf(A_log[d * DSN + n]) * 1.44269504088896f;
    for (int t = 0; t < CL; t++) {
      const unsigned* r = xrow + t * XROW;
      unsigned dtp = r[0];
      float x = fmaf(bhi(dtp), w1, fmaf(blo(dtp), w0, bd));
      float delta = softplus_fast(x);
      float uu = us2f(up[(size_t)t * DI]);
      float Bv[16], Cv[16];
      unpack8(((const uint4*)(r + 4))[0], Bv);
      unpack8(((const uint4*)(r + 4))[1], Bv + 8);
      unpack8(((const uint4*)(r + 12))[0], Cv);
      unpack8(((const uint4*)(r + 12))[1], Cv + 8);
      float du = delta * uu;
      float y = 0.f;
#pragma unroll
      for (int n = 0; n < DSN; n++) {
        float e = EXP2F(delta * A2[n]);
        h[n] = fmaf(h[n], e, du * Bv[n]);
        y = fmaf(h[n], Cv[n], y);
      }
      bf rv = f2bf(y + uu * Dd);
      yout[t * 66] = *(unsigned short*)&rv;
    }
  }
  __syncthreads();
  // ---- gate + out_proj + residual (thread = (g, column j)); xn read from global, coalesced ----
  int j = d;
  const unsigned short* xnp = (const unsigned short*)xn_ws
                            + ((size_t)(b * CC + g * DM)) * LL + l0 + j;
  float acc[DI];
#pragma unroll
  for (int dd = 0; dd < DI; dd++) acc[dd] = 0.f;
#pragma unroll
  for (int c4 = 0; c4 < 4; c4++) {                 // z projection, r-chunked: acc64 + xc8 live
    float xc[8];
#pragma unroll
    for (int r8 = 0; r8 < 8; r8++)
      xc[r8] = us2f(xnp[(size_t)(c4 * 8 + r8) * LL]);   // lanes j consecutive -> coalesced 128B
#pragma unroll
    for (int dd = 0; dd < DI; dd++) {              // weights wave-uniform -> s_load
      const float* w = in_proj_w + (DI + dd) * DM + c4 * 8;
      float a = acc[dd];
#pragma unroll
      for (int r8 = 0; r8 < 8; r8++) a = fmaf(xc[r8], w[r8], a);
      acc[dd] = a;
    }
  }
  const unsigned* yrow = y2S + g * 2112 + j * 33;  // banks (j+k)%32 -> conflict-free
#pragma unroll
  for (int k = 0; k < 32; k++) {                   // gate: y3 = y2 * silu(z)
    unsigned v = yrow[k];
    float z0 = acc[2 * k], z1 = acc[2 * k + 1];
    acc[2 * k]     = blo(v) * (z0 * sigmoidf_(z0));
    acc[2 * k + 1] = bhi(v) * (z1 * sigmoidf_(z1));
  }
  float* ob = out + ((size_t)(b * CC + g * DM)) * LL + l0 + j;
  for (int jj = 0; jj < DM; jj++) {                // out_proj + residual (residual read coalesced)
    const float* w = out_proj_w + jj * DI;
    float a = us2f(xnp[(size_t)jj * LL]);
#pragma unroll
    for (int dd = 0; dd < DI; dd++) a = fmaf(acc[dd], w[dd], a);
    ob[(size_t)jj * LL] = a;                       // coalesced 256B
  }
}

extern "C" void kernel_launch(void* const* d_in, const int* in_sizes, int n_in,
                              void* d_out, int out_size, void* d_ws, size_t ws_size,
                              hipStream_t stream) {
  const float* input     = (const float*)d_in[0];
  const float* ln_g      = (const float*)d_in[1];
  const float* ln_b      = (const float*)d_in[2];
  const float* in_proj_w = (const float*)d_in[3];
  const float* conv_w    = (const float*)d_in[4];
  const float* conv_b    = (const float*)d_in[5];
  const float* x_proj_w  = (const float*)d_in[6];
  const float* dt_proj_w = (const float*)d_in[7];
  const float* dt_proj_b = (const float*)d_in[8];
  const float* A_log     = (const float*)d_in[9];
  const float* Dw        = (const float*)d_in[10];
  const float* out_proj_w= (const float*)d_in[11];
  float* out = (float*)d_out;

  char* ws = (char*)d_ws;
  bf*       u_ws  = (bf*)(ws);                    // 32 MiB
  unsigned* xdbl  = (unsigned*)(ws + 33554432);   // 20 MiB
  bf*       xn_ws = (bf*)(ws + 54525952);         // 16 MiB
  float*    hloc  = (float*)(ws + 71303168);      // 16 MiB (hin aliases after k4)
  float*    ssum  = (float*)(ws + 88080384);      // 1 MiB
  (void)in_sizes; (void)n_in; (void)out_size; (void)ws_size;

  hipLaunchKernelGGL(k1_ln_conv, dim3(BB * NT), dim3(256), 0, stream,
                     input, ln_g, ln_b, in_proj_w, conv_w, conv_b, u_ws, xn_ws);
  hipLaunchKernelGGL(k2_xproj, dim3(1024), dim3(256), 0, stream,
                     u_ws, x_proj_w, xdbl);
  hipLaunchKernelGGL(k3_scanA, dim3(GG * NC), dim3(64), 0, stream,
                     xdbl, u_ws, A_log, dt_proj_w, dt_proj_b, hloc, ssum);
  hipLaunchKernelGGL(k4_combine, dim3(GG), dim3(64), 0, stream,
                     ssum, A_log, hloc);
  hipLaunchKernelGGL(k56_scan_final, dim3(BB * NC), dim3(256), 0, stream,
                     xdbl, u_ws, A_log, dt_proj_w, dt_proj_b, Dw, hloc, xn_ws,
                     in_proj_w, out_proj_w, out);
}